// Round 2
// baseline (137.305 us; speedup 1.0000x reference)
//
#include <hip/hip_runtime.h>
#include <hip/hip_cooperative_groups.h>

namespace cg = cooperative_groups;

// ---------------------------------------------------------------------------
// HybridQFCModel fused single cooperative kernel:
//   phase 1: avg_pool(6) row 0 -> 4 RX angles -> 4-qubit circuit -> <Z_i>,
//            per-block partial {sum o, sum o^2} to workspace
//   grid.sync()
//   phase 2: every block reduces all partials identically (double, fixed
//            order -> deterministic & consistent), applies BN affine to the
//            register-resident o[4], writes d_out once.
// Only floats 0..163 (rows 0..5, cols 0..23) of each 28x28 image are used.
// ---------------------------------------------------------------------------

__global__ __launch_bounds__(256, 2) void qfc_fused(
    const float* __restrict__ x,
    const float* __restrict__ qp,     // [2][4][2]
    const float* __restrict__ gamma,  // [4]
    const float* __restrict__ beta,   // [4]
    float* __restrict__ out,          // [B][4]
    float* __restrict__ partials,     // [gridDim.x][8]
    int B)
{
    const int tid = threadIdx.x;
    const int b = blockIdx.x * 256 + tid;
    const float* px = x + (size_t)b * 784;

    // --- pooling: first pooled row = rows 0..5, col groups of 6
    float enc[4] = {0.f, 0.f, 0.f, 0.f};
    #pragma unroll
    for (int r = 0; r < 6; ++r) {
        const float4* row = (const float4*)(px + r * 28);
        #pragma unroll
        for (int q = 0; q < 6; ++q) {
            float4 v = row[q];
            const int c0 = q * 4;
            enc[(c0 + 0) / 6] += v.x;
            enc[(c0 + 1) / 6] += v.y;
            enc[(c0 + 2) / 6] += v.z;
            enc[(c0 + 3) / 6] += v.w;
        }
    }

    // --- RX(enc/36) product state; amp(idx) = m * (-i)^k
    float ch[4], sh[4];
    #pragma unroll
    for (int w = 0; w < 4; ++w) {
        float h = enc[w] * (0.5f / 36.0f);
        __sincosf(h, &sh[w], &ch[w]);
    }

    float sr[16], si[16];
    #pragma unroll
    for (int idx = 0; idx < 16; ++idx) {
        float m = 1.f; int k = 0;
        #pragma unroll
        for (int w = 0; w < 4; ++w) {
            if ((idx >> (3 - w)) & 1) { m *= sh[w]; ++k; }
            else                        m *= ch[w];
        }
        switch (k & 3) {
            case 0:  sr[idx] =  m;  si[idx] = 0.f; break;
            case 1:  sr[idx] = 0.f; si[idx] = -m;  break;
            case 2:  sr[idx] = -m;  si[idx] = 0.f; break;
            default: sr[idx] = 0.f; si[idx] =  m;  break;
        }
    }

    #pragma unroll
    for (int l = 0; l < 2; ++l) {
        // RZ layer
        #pragma unroll
        for (int w = 0; w < 4; ++w) {
            float a = 0.5f * qp[l * 8 + w * 2 + 0];
            float sa, ca; __sincosf(a, &sa, &ca);
            #pragma unroll
            for (int idx = 0; idx < 16; ++idx) {
                float sg = ((idx >> (3 - w)) & 1) ? sa : -sa;
                float r = sr[idx], mm = si[idx];
                sr[idx] = r * ca - mm * sg;
                si[idx] = r * sg + mm * ca;
            }
        }
        // CNOT chain
        #pragma unroll
        for (int c = 0; c < 3; ++c) {
            const int t = c + 1;
            #pragma unroll
            for (int idx = 0; idx < 16; ++idx) {
                if ((((idx >> (3 - c)) & 1) == 1) && (((idx >> (3 - t)) & 1) == 0)) {
                    const int j = idx | (1 << (3 - t));
                    float tr = sr[idx]; sr[idx] = sr[j]; sr[j] = tr;
                    float ti = si[idx]; si[idx] = si[j]; si[j] = ti;
                }
            }
        }
        // RY layer
        #pragma unroll
        for (int w = 0; w < 4; ++w) {
            float bb = 0.5f * qp[l * 8 + w * 2 + 1];
            float sb, cb; __sincosf(bb, &sb, &cb);
            #pragma unroll
            for (int idx = 0; idx < 16; ++idx) {
                if (((idx >> (3 - w)) & 1) == 0) {
                    const int j = idx | (1 << (3 - w));
                    float r0 = sr[idx], r1 = sr[j];
                    sr[idx] = cb * r0 - sb * r1;
                    sr[j]   = sb * r0 + cb * r1;
                    float i0 = si[idx], i1 = si[j];
                    si[idx] = cb * i0 - sb * i1;
                    si[j]   = sb * i0 + cb * i1;
                }
            }
        }
    }

    // --- <Z_w>
    float o[4] = {0.f, 0.f, 0.f, 0.f};
    #pragma unroll
    for (int idx = 0; idx < 16; ++idx) {
        float p = sr[idx] * sr[idx] + si[idx] * si[idx];
        #pragma unroll
        for (int w = 0; w < 4; ++w)
            o[w] += ((idx >> (3 - w)) & 1) ? -p : p;
    }

    // --- per-block partial sums {o, o^2} (deterministic)
    {
        float vals[8] = { o[0], o[1], o[2], o[3],
                          o[0]*o[0], o[1]*o[1], o[2]*o[2], o[3]*o[3] };
        #pragma unroll
        for (int q = 0; q < 8; ++q) {
            float v = vals[q];
            #pragma unroll
            for (int off = 32; off > 0; off >>= 1)
                v += __shfl_down(v, off, 64);
            vals[q] = v;
        }
        __shared__ float red[4][8];
        const int lane = tid & 63;
        const int wv   = tid >> 6;
        if (lane == 0) {
            #pragma unroll
            for (int q = 0; q < 8; ++q) red[wv][q] = vals[q];
        }
        __syncthreads();
        if (tid == 0) {
            #pragma unroll
            for (int q = 0; q < 8; ++q)
                partials[(size_t)blockIdx.x * 8 + q] =
                    red[0][q] + red[1][q] + red[2][q] + red[3][q];
        }
    }

    __threadfence();            // device-scope release of partials
    cg::this_grid().sync();     // all partials visible to all blocks

    // --- phase 2: every block reduces all partials (identical fixed order)
    const int nblk = gridDim.x;
    double acc[8];
    #pragma unroll
    for (int q = 0; q < 8; ++q) acc[q] = 0.0;
    for (int r = tid; r < nblk; r += 256) {
        #pragma unroll
        for (int q = 0; q < 8; ++q) acc[q] += (double)partials[(size_t)r * 8 + q];
    }
    #pragma unroll
    for (int q = 0; q < 8; ++q) {
        double v = acc[q];
        #pragma unroll
        for (int off = 32; off > 0; off >>= 1)
            v += __shfl_down(v, off, 64);
        acc[q] = v;
    }
    __shared__ double dred[4][8];
    __shared__ float sstats[8];
    {
        const int lane = tid & 63;
        const int wv   = tid >> 6;
        if (lane == 0) {
            #pragma unroll
            for (int q = 0; q < 8; ++q) dred[wv][q] = acc[q];
        }
        __syncthreads();
        if (tid == 0) {
            const double invB = 1.0 / (double)B;
            #pragma unroll
            for (int w = 0; w < 4; ++w) {
                double s  = dred[0][w]     + dred[1][w]     + dred[2][w]     + dred[3][w];
                double s2 = dred[0][4 + w] + dred[1][4 + w] + dred[2][4 + w] + dred[3][4 + w];
                double mean = s * invB;
                double var  = s2 * invB - mean * mean;
                double scl  = (double)gamma[w] / sqrt(var + 1e-5);
                sstats[w]     = (float)scl;
                sstats[4 + w] = (float)((double)beta[w] - mean * scl);
            }
        }
        __syncthreads();
    }

    // --- apply BN affine, single coalesced out write
    float4 ov;
    ov.x = o[0] * sstats[0] + sstats[4];
    ov.y = o[1] * sstats[1] + sstats[5];
    ov.z = o[2] * sstats[2] + sstats[6];
    ov.w = o[3] * sstats[3] + sstats[7];
    ((float4*)out)[b] = ov;
}

extern "C" void kernel_launch(void* const* d_in, const int* in_sizes, int n_in,
                              void* d_out, int out_size, void* d_ws, size_t ws_size,
                              hipStream_t stream)
{
    const float* x  = (const float*)d_in[0];   // [B,1,28,28] f32
    const float* qp = (const float*)d_in[1];   // [2,4,2]
    const float* gm = (const float*)d_in[2];   // [4]
    const float* bt = (const float*)d_in[3];   // [4]
    float* out = (float*)d_out;                // [B,4] f32

    int B    = in_sizes[0] / 784;              // 131072
    int nblk = B / 256;                        // 512 (2 blocks/CU -> co-resident)

    float* partials = (float*)d_ws;            // nblk*8 floats

    void* args[] = { (void*)&x, (void*)&qp, (void*)&gm, (void*)&bt,
                     (void*)&out, (void*)&partials, (void*)&B };
    hipLaunchCooperativeKernel((void*)qfc_fused, dim3(nblk), dim3(256),
                               args, 0, stream);
}

// Round 3
// 30.926 us; speedup vs baseline: 4.4398x; 4.4398x over previous
//
#include <hip/hip_runtime.h>

// ---------------------------------------------------------------------------
// HybridQFCModel, 2-kernel structure:
//  k1 (qfc_main): 2 threads/image. Each loads 3 rows (rows 0-2 / 3-5, cols
//     0..23), pair-combines the 4 pooled sums via shfl_xor, both threads run
//     the 4-qubit circuit redundantly; even thread writes pre-BN out; odd
//     thread contributes 0 to block partial sums {sum o, sum o^2}.
//  k2 (qfc_stats_bn): every block redundantly reduces all partials in a fixed
//     order (double) -> identical BN scale/shift everywhere, then applies the
//     affine to its slice of out. No grid sync, no atomics: deterministic.
// Only floats 0..163 (rows 0..5, cols 0..23) of each 28x28 image are used.
// ---------------------------------------------------------------------------

__global__ __launch_bounds__(256) void qfc_main(
    const float* __restrict__ x,
    const float* __restrict__ qp,     // [2][4][2]
    float* __restrict__ out,          // [B][4] pre-BN
    float* __restrict__ partials)     // [gridDim.x][8]
{
    const int tid  = threadIdx.x;
    const int gt   = blockIdx.x * 256 + tid;
    const int b    = gt >> 1;          // image index
    const int half = gt & 1;           // 0: rows 0-2, 1: rows 3-5
    const float* px = x + (size_t)b * 784 + half * (3 * 28);

    // --- partial pooling over this thread's 3 rows
    float enc[4] = {0.f, 0.f, 0.f, 0.f};
    #pragma unroll
    for (int r = 0; r < 3; ++r) {
        const float4* row = (const float4*)(px + r * 28);
        #pragma unroll
        for (int q = 0; q < 6; ++q) {
            float4 v = row[q];
            const int c0 = q * 4;
            enc[(c0 + 0) / 6] += v.x;
            enc[(c0 + 1) / 6] += v.y;
            enc[(c0 + 2) / 6] += v.z;
            enc[(c0 + 3) / 6] += v.w;
        }
    }
    // --- combine halves (pair lanes 2i, 2i+1)
    #pragma unroll
    for (int j = 0; j < 4; ++j)
        enc[j] += __shfl_xor(enc[j], 1, 64);

    // --- RX(enc/36) product state; amp(idx) = m * (-i)^k
    float ch[4], sh[4];
    #pragma unroll
    for (int w = 0; w < 4; ++w) {
        float h = enc[w] * (0.5f / 36.0f);
        __sincosf(h, &sh[w], &ch[w]);
    }

    float sr[16], si[16];
    #pragma unroll
    for (int idx = 0; idx < 16; ++idx) {
        float m = 1.f; int k = 0;
        #pragma unroll
        for (int w = 0; w < 4; ++w) {
            if ((idx >> (3 - w)) & 1) { m *= sh[w]; ++k; }
            else                        m *= ch[w];
        }
        switch (k & 3) {
            case 0:  sr[idx] =  m;  si[idx] = 0.f; break;
            case 1:  sr[idx] = 0.f; si[idx] = -m;  break;
            case 2:  sr[idx] = -m;  si[idx] = 0.f; break;
            default: sr[idx] = 0.f; si[idx] =  m;  break;
        }
    }

    #pragma unroll
    for (int l = 0; l < 2; ++l) {
        // RZ layer
        #pragma unroll
        for (int w = 0; w < 4; ++w) {
            float a = 0.5f * qp[l * 8 + w * 2 + 0];
            float sa, ca; __sincosf(a, &sa, &ca);
            #pragma unroll
            for (int idx = 0; idx < 16; ++idx) {
                float sg = ((idx >> (3 - w)) & 1) ? sa : -sa;
                float r = sr[idx], mm = si[idx];
                sr[idx] = r * ca - mm * sg;
                si[idx] = r * sg + mm * ca;
            }
        }
        // CNOT chain
        #pragma unroll
        for (int c = 0; c < 3; ++c) {
            const int t = c + 1;
            #pragma unroll
            for (int idx = 0; idx < 16; ++idx) {
                if ((((idx >> (3 - c)) & 1) == 1) && (((idx >> (3 - t)) & 1) == 0)) {
                    const int j = idx | (1 << (3 - t));
                    float tr = sr[idx]; sr[idx] = sr[j]; sr[j] = tr;
                    float ti = si[idx]; si[idx] = si[j]; si[j] = ti;
                }
            }
        }
        // RY layer
        #pragma unroll
        for (int w = 0; w < 4; ++w) {
            float bb = 0.5f * qp[l * 8 + w * 2 + 1];
            float sb, cb; __sincosf(bb, &sb, &cb);
            #pragma unroll
            for (int idx = 0; idx < 16; ++idx) {
                if (((idx >> (3 - w)) & 1) == 0) {
                    const int j = idx | (1 << (3 - w));
                    float r0 = sr[idx], r1 = sr[j];
                    sr[idx] = cb * r0 - sb * r1;
                    sr[j]   = sb * r0 + cb * r1;
                    float i0 = si[idx], i1 = si[j];
                    si[idx] = cb * i0 - sb * i1;
                    si[j]   = sb * i0 + cb * i1;
                }
            }
        }
    }

    // --- <Z_w>
    float o[4] = {0.f, 0.f, 0.f, 0.f};
    #pragma unroll
    for (int idx = 0; idx < 16; ++idx) {
        float p = sr[idx] * sr[idx] + si[idx] * si[idx];
        #pragma unroll
        for (int w = 0; w < 4; ++w)
            o[w] += ((idx >> (3 - w)) & 1) ? -p : p;
    }

    // --- pre-BN store: even lanes only; their float4s are contiguous
    if (half == 0) {
        float4 ov; ov.x = o[0]; ov.y = o[1]; ov.z = o[2]; ov.w = o[3];
        ((float4*)out)[b] = ov;
    }

    // --- per-block partials; odd lanes contribute 0 (image counted once)
    const float g = (half == 0) ? 1.f : 0.f;
    float vals[8] = { g*o[0], g*o[1], g*o[2], g*o[3],
                      g*o[0]*o[0], g*o[1]*o[1], g*o[2]*o[2], g*o[3]*o[3] };
    #pragma unroll
    for (int q = 0; q < 8; ++q) {
        float v = vals[q];
        #pragma unroll
        for (int off = 32; off > 0; off >>= 1)
            v += __shfl_down(v, off, 64);
        vals[q] = v;
    }
    __shared__ float red[4][8];
    const int lane = tid & 63;
    const int wv   = tid >> 6;
    if (lane == 0) {
        #pragma unroll
        for (int q = 0; q < 8; ++q) red[wv][q] = vals[q];
    }
    __syncthreads();
    if (tid == 0) {
        #pragma unroll
        for (int q = 0; q < 8; ++q)
            partials[(size_t)blockIdx.x * 8 + q] =
                red[0][q] + red[1][q] + red[2][q] + red[3][q];
    }
}

// Every block redundantly reduces all partials (fixed order, double) ->
// identical stats; applies BN affine to its out slice.
__global__ __launch_bounds__(256) void qfc_stats_bn(
    const float* __restrict__ partials,
    const float* __restrict__ gamma,
    const float* __restrict__ beta,
    float* __restrict__ out,
    int nprt, int B)
{
    const int tid = threadIdx.x;
    double acc[8];
    #pragma unroll
    for (int q = 0; q < 8; ++q) acc[q] = 0.0;
    for (int r = tid; r < nprt; r += 256) {
        #pragma unroll
        for (int q = 0; q < 8; ++q) acc[q] += (double)partials[(size_t)r * 8 + q];
    }
    #pragma unroll
    for (int q = 0; q < 8; ++q) {
        double v = acc[q];
        #pragma unroll
        for (int off = 32; off > 0; off >>= 1)
            v += __shfl_down(v, off, 64);
        acc[q] = v;
    }
    __shared__ double dred[4][8];
    __shared__ float sstats[8];
    const int lane = tid & 63;
    const int wv   = tid >> 6;
    if (lane == 0) {
        #pragma unroll
        for (int q = 0; q < 8; ++q) dred[wv][q] = acc[q];
    }
    __syncthreads();
    if (tid == 0) {
        const double invB = 1.0 / (double)B;
        #pragma unroll
        for (int w = 0; w < 4; ++w) {
            double s  = dred[0][w]     + dred[1][w]     + dred[2][w]     + dred[3][w];
            double s2 = dred[0][4 + w] + dred[1][4 + w] + dred[2][4 + w] + dred[3][4 + w];
            double mean = s * invB;
            double var  = s2 * invB - mean * mean;
            double scl  = (double)gamma[w] / sqrt(var + 1e-5);
            sstats[w]     = (float)scl;
            sstats[4 + w] = (float)((double)beta[w] - mean * scl);
        }
    }
    __syncthreads();

    const int b = blockIdx.x * 256 + tid;
    float4 v = ((float4*)out)[b];
    v.x = v.x * sstats[0] + sstats[4];
    v.y = v.y * sstats[1] + sstats[5];
    v.z = v.z * sstats[2] + sstats[6];
    v.w = v.w * sstats[3] + sstats[7];
    ((float4*)out)[b] = v;
}

extern "C" void kernel_launch(void* const* d_in, const int* in_sizes, int n_in,
                              void* d_out, int out_size, void* d_ws, size_t ws_size,
                              hipStream_t stream)
{
    const float* x  = (const float*)d_in[0];   // [B,1,28,28] f32
    const float* qp = (const float*)d_in[1];   // [2,4,2]
    const float* gm = (const float*)d_in[2];   // [4]
    const float* bt = (const float*)d_in[3];   // [4]
    float* out = (float*)d_out;                // [B,4] f32

    const int B     = in_sizes[0] / 784;       // 131072
    const int nblk1 = (B * 2) / 256;           // 1024 (2 threads/image)
    const int nblk2 = B / 256;                 // 512

    float* partials = (float*)d_ws;            // nblk1*8 floats = 32 KB

    qfc_main    <<<nblk1, 256, 0, stream>>>(x, qp, out, partials);
    qfc_stats_bn<<<nblk2, 256, 0, stream>>>(partials, gm, bt, out, nblk1, B);
}